// Round 5
// baseline (37315.060 us; speedup 1.0000x reference)
//
#include <hip/hip_runtime.h>

// 16-qubit statevector sim, 512 samples, one sample per 512-thread block.
// amp index i (16 bits): bits 0..6 = thread-local (128 amps/thread),
// bits 7..12 = lane (tid&63), bits 13..15 = wave (tid>>6). Qubit q <-> bit 15-q.
// State: amps 0..95 in REGISTERS as 12 x ext_vector_type(16) (SSA values --
// cannot be demoted to scratch; round-4's float[96] arrays went to scratch =
// 82 GB HBM traffic), amps 96..127 in LDS sL[amp-96][tid].

#define NREG 96
#define NLDS 32
#define NTH  512
#define SMEM_BYTES (NLDS * NTH * 8 + 2 * NTH * 16)  // 131072 + 16384 = 147456

typedef float v16f __attribute__((ext_vector_type(16)));

struct RS {  // register-resident state: amps 0..95, 192 VGPRs
  v16f a0, a1, a2, a3, a4, a5;   // real
  v16f b0, b1, b2, b3, b4, b5;   // imag
};

template <int I>
__device__ __forceinline__ float2 rld(const RS& s) {
  static_assert(I >= 0 && I < NREG, "reg amp idx");
  constexpr int e = I & 15;
  if constexpr (I < 16)      return make_float2(s.a0[e], s.b0[e]);
  else if constexpr (I < 32) return make_float2(s.a1[e], s.b1[e]);
  else if constexpr (I < 48) return make_float2(s.a2[e], s.b2[e]);
  else if constexpr (I < 64) return make_float2(s.a3[e], s.b3[e]);
  else if constexpr (I < 80) return make_float2(s.a4[e], s.b4[e]);
  else                       return make_float2(s.a5[e], s.b5[e]);
}

template <int I>
__device__ __forceinline__ void rst(RS& s, float2 v) {
  static_assert(I >= 0 && I < NREG, "reg amp idx");
  constexpr int e = I & 15;
  if constexpr (I < 16)      { s.a0[e] = v.x; s.b0[e] = v.y; }
  else if constexpr (I < 32) { s.a1[e] = v.x; s.b1[e] = v.y; }
  else if constexpr (I < 48) { s.a2[e] = v.x; s.b2[e] = v.y; }
  else if constexpr (I < 64) { s.a3[e] = v.x; s.b3[e] = v.y; }
  else if constexpr (I < 80) { s.a4[e] = v.x; s.b4[e] = v.y; }
  else                       { s.a5[e] = v.x; s.b5[e] = v.y; }
}

template <int I> struct IC { static constexpr int value = I; };

template <int N, int I = 0, typename F>
__device__ __forceinline__ void static_for(F&& f) {
  if constexpr (I < N) {
    f(IC<I>{});
    static_for<N, I + 1>(f);
  }
}

template <int P> __device__ constexpr int ins0(int h) {
  return ((h >> P) << (P + 1)) | (h & ((1 << P) - 1));
}

#define SARGS RS& rs, float2 (*sL)[NTH], float4 (*stg)[NTH], const int tid
#define SPASS rs, sL, stg, tid

template <int L>
__device__ __forceinline__ float2 ldS(SARGS) {
  static_assert(L >= 0 && L < 128, "amp idx");
  if constexpr (L < NREG) return rld<L>(rs);
  else return sL[L - NREG][tid];
}

template <int L>
__device__ __forceinline__ void stS(SARGS, float2 v) {
  static_assert(L >= 0 && L < 128, "amp idx");
  if constexpr (L < NREG) rst<L>(rs, v);
  else sL[L - NREG][tid] = v;
}

// ---------- Rot on local bit J (templated target, runtime u) ----------
template <int J>
__device__ __forceinline__ void rot_local(SARGS, const float* __restrict__ u) {
  const float u00r = u[0], u00i = u[1], u01r = u[2], u01i = u[3];
  const float u10r = u[4], u10i = u[5], u11r = u[6], u11i = u[7];
  static_for<64>([&](auto hc) {
    constexpr int h = hc.value;
    constexpr int i0 = ins0<J>(h);
    constexpr int i1 = i0 | (1 << J);
    const float2 a = ldS<i0>(SPASS);
    const float2 b = ldS<i1>(SPASS);
    float2 n0, n1;
    n0.x = u00r * a.x - u00i * a.y + u01r * b.x - u01i * b.y;
    n0.y = u00r * a.y + u00i * a.x + u01r * b.y + u01i * b.x;
    n1.x = u10r * a.x - u10i * a.y + u11r * b.x - u11i * b.y;
    n1.y = u10r * a.y + u10i * a.x + u11r * b.y + u11i * b.x;
    stS<i0>(SPASS, n0);
    stS<i1>(SPASS, n1);
  });
}

// ---------- Rot on lane bit (runtime lane-bit index jm in [0,6)) ----------
__device__ __forceinline__ void rot_lane(SARGS, const float* __restrict__ u, const int jm) {
  const int m = 1 << jm;
  const int bit = (tid >> jm) & 1;
  const float car = bit ? u[6] : u[0], cai = bit ? u[7] : u[1];
  const float cbr = bit ? u[4] : u[2], cbi = bit ? u[5] : u[3];
  static_for<NREG>([&](auto ic) {
    constexpr int i = ic.value;
    const float2 o = rld<i>(rs);
    const float pr = __shfl_xor(o.x, m);
    const float pi = __shfl_xor(o.y, m);
    float2 n;
    n.x = car * o.x - cai * o.y + cbr * pr - cbi * pi;
    n.y = car * o.y + cai * o.x + cbr * pi + cbi * pr;
    rst<i>(rs, n);
  });
  static_for<NLDS>([&](auto kc) {
    constexpr int k = kc.value;
    const float2 o = sL[k][tid];
    const float px = __shfl_xor(o.x, m);
    const float py = __shfl_xor(o.y, m);
    float2 n;
    n.x = car * o.x - cai * o.y + cbr * px - cbi * py;
    n.y = car * o.y + cai * o.x + cbr * py + cbi * px;
    sL[k][tid] = n;
  });
}

// ---------- Rot on wave bit (runtime tid-bit index jt in [6,9)) ----------
__device__ __forceinline__ void rot_wave(SARGS, const float* __restrict__ u, const int jt) {
  const int tm = 1 << jt;
  const int pt = tid ^ tm;
  const int bit = (tid >> jt) & 1;
  const float car = bit ? u[6] : u[0], cai = bit ? u[7] : u[1];
  const float cbr = bit ? u[4] : u[2], cbi = bit ? u[5] : u[3];
  static_for<NREG / 4>([&](auto cc) {
    constexpr int c4 = cc.value * 4;
    const float2 o0 = rld<c4 + 0>(rs), o1 = rld<c4 + 1>(rs);
    const float2 o2 = rld<c4 + 2>(rs), o3 = rld<c4 + 3>(rs);
    stg[0][tid] = make_float4(o0.x, o0.y, o1.x, o1.y);
    stg[1][tid] = make_float4(o2.x, o2.y, o3.x, o3.y);
    __syncthreads();
    const float4 p0 = stg[0][pt];
    const float4 p1 = stg[1][pt];
    __syncthreads();
    const float2 os[4] = {o0, o1, o2, o3};
    const float prs[4] = {p0.x, p0.z, p1.x, p1.z};
    const float pis[4] = {p0.y, p0.w, p1.y, p1.w};
    static_for<4>([&](auto tc) {
      constexpr int t = tc.value;
      float2 n;
      n.x = car * os[t].x - cai * os[t].y + cbr * prs[t] - cbi * pis[t];
      n.y = car * os[t].y + cai * os[t].x + cbr * pis[t] + cbi * prs[t];
      rst<c4 + t>(rs, n);
    });
  });
  static_for<NLDS / 8>([&](auto cc) {
    constexpr int c8 = cc.value * 8;
    float2 nv[8];
    static_for<8>([&](auto jc) {
      constexpr int k = c8 + jc.value;
      const float2 o = sL[k][tid];
      const float2 p = sL[k][pt];
      float2 n;
      n.x = car * o.x - cai * o.y + cbr * p.x - cbi * p.y;
      n.y = car * o.y + cai * o.x + cbr * p.y + cbi * p.x;
      nv[jc.value] = n;
    });
    __syncthreads();
    static_for<8>([&](auto jc) { sL[c8 + jc.value][tid] = nv[jc.value]; });
    __syncthreads();
  });
}

// ---------- CNOT, local-bit target TJ (templated), runtime control cj ----------
template <int TJ>
__device__ __forceinline__ void cnot_local_t(SARGS, const int cj) {
  const int tb7 = tid << 7;
  static_for<64>([&](auto hc) {
    constexpr int h = hc.value;
    constexpr int i0 = ins0<TJ>(h);
    constexpr int i1 = i0 | (1 << TJ);
    const int take = ((i0 | tb7) >> cj) & 1;  // cj != TJ, so same for i0/i1
    const float2 a = ldS<i0>(SPASS);
    const float2 b = ldS<i1>(SPASS);
    const float2 n0 = take ? b : a;
    const float2 n1 = take ? a : b;
    stS<i0>(SPASS, n0);
    stS<i1>(SPASS, n1);
  });
}

// ---------- CNOT, lane-bit target (runtime jm in [0,6)), runtime control ----------
__device__ __forceinline__ void cnot_lane_t(SARGS, const int cj, const int jm) {
  const int m = 1 << jm;
  const int tb7 = tid << 7;
  static_for<NREG>([&](auto ic) {
    constexpr int i = ic.value;
    const int take = ((i | tb7) >> cj) & 1;
    const float2 o = rld<i>(rs);
    const float pr = __shfl_xor(o.x, m);
    const float pi = __shfl_xor(o.y, m);
    float2 n;
    n.x = take ? pr : o.x;
    n.y = take ? pi : o.y;
    rst<i>(rs, n);
  });
  static_for<NLDS>([&](auto kc) {
    constexpr int k = kc.value;
    const int take = (((NREG + k) | tb7) >> cj) & 1;
    const float2 o = sL[k][tid];
    const float px = __shfl_xor(o.x, m);
    const float py = __shfl_xor(o.y, m);
    float2 n;
    n.x = take ? px : o.x;
    n.y = take ? py : o.y;
    sL[k][tid] = n;
  });
}

// ---------- CNOT, wave-bit target (runtime jt in [6,9)), runtime control ----------
__device__ __forceinline__ void cnot_wave_t(SARGS, const int cj, const int jt) {
  const int tm = 1 << jt;
  const int pt = tid ^ tm;
  const int tb7 = tid << 7;
  static_for<NREG / 4>([&](auto cc) {
    constexpr int c4 = cc.value * 4;
    const float2 o0 = rld<c4 + 0>(rs), o1 = rld<c4 + 1>(rs);
    const float2 o2 = rld<c4 + 2>(rs), o3 = rld<c4 + 3>(rs);
    stg[0][tid] = make_float4(o0.x, o0.y, o1.x, o1.y);
    stg[1][tid] = make_float4(o2.x, o2.y, o3.x, o3.y);
    __syncthreads();
    const float4 p0 = stg[0][pt];
    const float4 p1 = stg[1][pt];
    __syncthreads();
    const float2 os[4] = {o0, o1, o2, o3};
    const float prs[4] = {p0.x, p0.z, p1.x, p1.z};
    const float pis[4] = {p0.y, p0.w, p1.y, p1.w};
    static_for<4>([&](auto tc) {
      constexpr int t = tc.value;
      constexpr int a = c4 + t;
      const int take = ((a | tb7) >> cj) & 1;
      float2 n;
      n.x = take ? prs[t] : os[t].x;
      n.y = take ? pis[t] : os[t].y;
      rst<a>(rs, n);
    });
  });
  static_for<NLDS / 8>([&](auto cc) {
    constexpr int c8 = cc.value * 8;
    float2 nv[8];
    static_for<8>([&](auto jc) {
      constexpr int k = c8 + jc.value;
      const int take = (((NREG + k) | tb7) >> cj) & 1;
      const float2 o = sL[k][tid];
      const float2 p = sL[k][pt];
      float2 n;
      n.x = take ? p.x : o.x;
      n.y = take ? p.y : o.y;
      nv[jc.value] = n;
    });
    __syncthreads();
    static_for<8>([&](auto jc) { sL[c8 + jc.value][tid] = nv[jc.value]; });
    __syncthreads();
  });
}

// Precompute ALL Rot matrices (layers 0..5, batch-shared) into workspace.
__global__ void qsim_prep(const float* __restrict__ w, float* __restrict__ gm) {
  const int i = threadIdx.x;
  if (i < 96) {
    const float phi = w[i * 3 + 0];
    const float th  = w[i * 3 + 1];
    const float om  = w[i * 3 + 2];
    float st, ct; sincosf(0.5f * th, &st, &ct);
    float sa, ca; sincosf(0.5f * (phi + om), &sa, &ca);
    float sb, cb; sincosf(0.5f * (phi - om), &sb, &cb);
    float* u = gm + i * 8;
    u[0] =  ct * ca; u[1] = -ct * sa;   // m00
    u[2] = -st * cb; u[3] = -st * sb;   // m01
    u[4] =  st * cb; u[5] = -st * sb;   // m10
    u[6] =  ct * ca; u[7] =  ct * sa;   // m11
  }
}

__global__ void __launch_bounds__(NTH)
__attribute__((amdgpu_waves_per_eu(2, 2)))
qsim_main(const float* __restrict__ x,
          const float* __restrict__ gmG,
          float* __restrict__ out) {
  extern __shared__ char smem_raw[];
  float2 (*sL)[NTH]  = reinterpret_cast<float2(*)[NTH]>(smem_raw);
  float4 (*stg)[NTH] = reinterpret_cast<float4(*)[NTH]>(smem_raw + NLDS * NTH * 8);
  float  (*iv)[4]    = reinterpret_cast<float(*)[4]>(smem_raw + NLDS * NTH * 8);   // aliases stg (init only)
  float  (*red)[16]  = reinterpret_cast<float(*)[16]>(smem_raw + NLDS * NTH * 8);  // aliases stg (epilogue only)

  const int tid = threadIdx.x;
  const int b = blockIdx.x;

  // per-qubit init vector: v = RX(x[b][q]) * |0> = [cos(x/2), -i sin(x/2)]
  if (tid < 16) {
    const int q = tid;
    float xs, xc; sincosf(0.5f * x[b * 16 + q], &xs, &xc);
    iv[q][0] = xc;
    iv[q][1] = 0.f;
    iv[q][2] = 0.f;
    iv[q][3] = -xs;
  }
  __syncthreads();

  RS rs;

  // thread-uniform factor over bits 7..15 (qubits 8..0)
  float Fr = 1.f, Fi = 0.f;
  #pragma unroll
  for (int j = 7; j < 16; ++j) {
    const int q = 15 - j;
    const int bt = (tid >> (j - 7)) & 1;
    const float fr = iv[q][2 * bt], fi = iv[q][2 * bt + 1];
    const float nr = Fr * fr - Fi * fi;
    Fi = Fr * fi + Fi * fr;
    Fr = nr;
  }

  // local tensor doubling over bits 0..6 (qubits 15..9)
  stS<0>(SPASS, make_float2(Fr, Fi));
  static_for<7>([&](auto jc) {
    constexpr int j = jc.value;
    constexpr int m = 1 << j;
    constexpr int q = 15 - j;
    const float f0r = iv[q][0], f0i = iv[q][1];
    const float f1r = iv[q][2], f1i = iv[q][3];
    static_for<m>([&](auto kc) {
      constexpr int k = kc.value;
      const float2 a = ldS<k>(SPASS);
      stS<k | m>(SPASS, make_float2(a.x * f1r - a.y * f1i, a.x * f1i + a.y * f1r));
      stS<k>(SPASS, make_float2(a.x * f0r - a.y * f0i, a.x * f0i + a.y * f0r));
    });
  });
  __syncthreads();  // iv dead -> staging region free

  // 6 layers: 16 Rots (commute; applied j=0..15 i.e. qubit 15..0) then
  // CNOT ring control q=g, target (g+r)%16, r=l+1, in reference order.
  #pragma clang loop unroll(disable)
  for (int l = 0; l < 6; ++l) {
    const float* __restrict__ gmL = gmG + l * 128;
    #pragma clang loop unroll(disable)
    for (int j = 0; j < 16; ++j) {
      const float* __restrict__ u = gmL + (15 - j) * 8;
      if (j < 7) {
        switch (j) {
          case 0: rot_local<0>(SPASS, u); break;
          case 1: rot_local<1>(SPASS, u); break;
          case 2: rot_local<2>(SPASS, u); break;
          case 3: rot_local<3>(SPASS, u); break;
          case 4: rot_local<4>(SPASS, u); break;
          case 5: rot_local<5>(SPASS, u); break;
          default: rot_local<6>(SPASS, u); break;
        }
      } else if (j < 13) {
        rot_lane(SPASS, u, j - 7);
      } else {
        rot_wave(SPASS, u, j - 7);
      }
    }
    const int r = l + 1;
    #pragma clang loop unroll(disable)
    for (int g = 0; g < 16; ++g) {
      const int cj = 15 - g;
      const int tj = 15 - ((g + r) & 15);
      if (tj < 7) {
        switch (tj) {
          case 0: cnot_local_t<0>(SPASS, cj); break;
          case 1: cnot_local_t<1>(SPASS, cj); break;
          case 2: cnot_local_t<2>(SPASS, cj); break;
          case 3: cnot_local_t<3>(SPASS, cj); break;
          case 4: cnot_local_t<4>(SPASS, cj); break;
          case 5: cnot_local_t<5>(SPASS, cj); break;
          default: cnot_local_t<6>(SPASS, cj); break;
        }
      } else if (tj < 13) {
        cnot_lane_t(SPASS, cj, tj - 7);
      } else {
        cnot_wave_t(SPASS, cj, tj - 7);
      }
    }
  }

  // ---- measurement: <Z_q> ----
  float tot = 0.f;
  float sl0 = 0.f, sl1 = 0.f, sl2 = 0.f, sl3 = 0.f, sl4 = 0.f, sl5 = 0.f, sl6 = 0.f;
  static_for<128>([&](auto ic) {
    constexpr int i = ic.value;
    const float2 o = ldS<i>(SPASS);
    const float p = o.x * o.x + o.y * o.y;
    tot += p;
    if constexpr ((i & 1) != 0)  sl0 -= p; else sl0 += p;
    if constexpr ((i & 2) != 0)  sl1 -= p; else sl1 += p;
    if constexpr ((i & 4) != 0)  sl2 -= p; else sl2 += p;
    if constexpr ((i & 8) != 0)  sl3 -= p; else sl3 += p;
    if constexpr ((i & 16) != 0) sl4 -= p; else sl4 += p;
    if constexpr ((i & 32) != 0) sl5 -= p; else sl5 += p;
    if constexpr ((i & 64) != 0) sl6 -= p; else sl6 += p;
  });
  __syncthreads();

  const float sl[7] = {sl0, sl1, sl2, sl3, sl4, sl5, sl6};
  static_for<16>([&](auto qc) {
    constexpr int q = qc.value;
    constexpr int j = 15 - q;
    float v;
    if constexpr (j < 7) v = sl[j];
    else v = ((tid >> (j - 7)) & 1) ? -tot : tot;
    v += __shfl_xor(v, 1);
    v += __shfl_xor(v, 2);
    v += __shfl_xor(v, 4);
    v += __shfl_xor(v, 8);
    v += __shfl_xor(v, 16);
    v += __shfl_xor(v, 32);
    if ((tid & 63) == 0) red[tid >> 6][q] = v;
  });
  __syncthreads();
  if (tid < 16) {
    float a = 0.f;
    #pragma unroll
    for (int wv = 0; wv < 8; ++wv) a += red[wv][tid];
    out[b * 16 + tid] = a;
  }
}

extern "C" void kernel_launch(void* const* d_in, const int* in_sizes, int n_in,
                              void* d_out, int out_size, void* d_ws, size_t ws_size,
                              hipStream_t stream) {
  (void)in_sizes; (void)n_in; (void)out_size; (void)ws_size;
  const float* x = (const float*)d_in[0];
  const float* w = (const float*)d_in[1];
  float* out = (float*)d_out;
  float* gm = (float*)d_ws;  // 96*8 floats = 3072 B
  hipFuncSetAttribute(reinterpret_cast<const void*>(qsim_main),
                      hipFuncAttributeMaxDynamicSharedMemorySize, SMEM_BYTES);
  qsim_prep<<<dim3(1), dim3(128), 0, stream>>>(w, gm);
  qsim_main<<<dim3(512), dim3(NTH), SMEM_BYTES, stream>>>(x, gm, out);
}

// Round 7
// 3389.083 us; speedup vs baseline: 11.0104x; 11.0104x over previous
//
#include <hip/hip_runtime.h>

// 16-qubit statevector sim, 512 samples. STREAMING design: state lives in
// d_ws; each sweep kernel holds 16 amps/thread (32 VGPRs -- small enough that
// the compiler keeps it in registers; rounds 4/5 proved 192+ VGPR state gets
// demoted to scratch = 80-108 GB HBM traffic). Round 7: chunk the batch by
// available ws_size (round 6 wrote 256 MB into d_ws unchecked -> mem fault).
// Mapping: qubit q <-> bit q of amp index (self-consistent relabel of the
// reference's q <-> bit 15-q). Per layer (ring shift r=l+1):
//   Sweep P: tile bits 0..12 (fix 13..15): Rots q0..12, ring g in [0,13-r).
//   Sweep Q: tile bits 0..6,10..15 (fix 7..9): Rots q13..15, ring g in [13-r,16).
// Rots q13..15 commute with the prefix (prefix touches qubits 0..12 only);
// prefix+suffix are contiguous arcs of the ring in original order.

#define NTH 512
typedef float v16f __attribute__((ext_vector_type(16)));

template <int I> struct IC { static constexpr int value = I; };
template <int N, int I = 0, typename F>
__device__ __forceinline__ void static_for(F&& f) {
  if constexpr (I < N) { f(IC<I>{}); static_for<N, I + 1>(f); }
}

// ---------------- gate helpers on 16 reg amps (ar, ai) ----------------

template <int LB>  // Rot on local bit LB (0..3)
__device__ __forceinline__ void rot_local(v16f& ar, v16f& ai, const float* __restrict__ u) {
  const float u00r = u[0], u00i = u[1], u01r = u[2], u01i = u[3];
  const float u10r = u[4], u10i = u[5], u11r = u[6], u11i = u[7];
  static_for<8>([&](auto hc) {
    constexpr int h = hc.value;
    constexpr int e0 = ((h >> LB) << (LB + 1)) | (h & ((1 << LB) - 1));
    constexpr int e1 = e0 | (1 << LB);
    const float axr = ar[e0], axi = ai[e0], bxr = ar[e1], bxi = ai[e1];
    ar[e0] = u00r * axr - u00i * axi + u01r * bxr - u01i * bxi;
    ai[e0] = u00r * axi + u00i * axr + u01r * bxi + u01i * bxr;
    ar[e1] = u10r * axr - u10i * axi + u11r * bxr - u11i * bxi;
    ai[e1] = u10r * axi + u10i * axr + u11r * bxi + u11i * bxr;
  });
}

// Rot on a lane bit: runtime shuffle mask m (<64), bit = this lane's bit value
__device__ __forceinline__ void rot_lane(v16f& ar, v16f& ai, const float* __restrict__ u,
                                         const int m, const int bit) {
  const float car = bit ? u[6] : u[0], cai = bit ? u[7] : u[1];
  const float cbr = bit ? u[4] : u[2], cbi = bit ? u[5] : u[3];
  static_for<16>([&](auto ec) {
    constexpr int e = ec.value;
    const float orr = ar[e], oii = ai[e];
    const float pr = __shfl_xor(orr, m);
    const float pi = __shfl_xor(oii, m);
    ar[e] = car * orr - cai * oii + cbr * pr - cbi * pi;
    ai[e] = car * oii + cai * orr + cbr * pi + cbi * pr;
  });
}

// Rot on a wave bit: partner thread pt, barriered LDS exchange
__device__ __forceinline__ void rot_wave(v16f& ar, v16f& ai, const float* __restrict__ u,
                                         float2 (*ex)[NTH], const int tid, const int pt,
                                         const int bit) {
  const float car = bit ? u[6] : u[0], cai = bit ? u[7] : u[1];
  const float cbr = bit ? u[4] : u[2], cbi = bit ? u[5] : u[3];
  static_for<16>([&](auto ec) { constexpr int e = ec.value; ex[e][tid] = make_float2(ar[e], ai[e]); });
  __syncthreads();
  v16f prv, piv;
  static_for<16>([&](auto ec) { constexpr int e = ec.value; const float2 p = ex[e][pt]; prv[e] = p.x; piv[e] = p.y; });
  __syncthreads();
  static_for<16>([&](auto ec) {
    constexpr int e = ec.value;
    const float orr = ar[e], oii = ai[e];
    ar[e] = car * orr - cai * oii + cbr * prv[e] - cbi * piv[e];
    ai[e] = car * oii + cai * orr + cbr * piv[e] + cbi * prv[e];
  });
}

template <int TB>  // CNOT, local target bit TB (0..3), runtime control bit c
__device__ __forceinline__ void cnot_local(v16f& ar, v16f& ai, const int ibase, const int c) {
  static_for<8>([&](auto hc) {
    constexpr int h = hc.value;
    constexpr int e0 = ((h >> TB) << (TB + 1)) | (h & ((1 << TB) - 1));
    constexpr int e1 = e0 | (1 << TB);
    const int take = ((ibase | e0) >> c) & 1;  // c != TB: same for e0/e1
    const float axr = ar[e0], axi = ai[e0], bxr = ar[e1], bxi = ai[e1];
    ar[e0] = take ? bxr : axr; ai[e0] = take ? bxi : axi;
    ar[e1] = take ? axr : bxr; ai[e1] = take ? axi : bxi;
  });
}

__device__ __forceinline__ void cnot_lane(v16f& ar, v16f& ai, const int m,
                                          const int ibase, const int c) {
  static_for<16>([&](auto ec) {
    constexpr int e = ec.value;
    const int take = ((ibase | e) >> c) & 1;
    const float pr = __shfl_xor(ar[e], m);
    const float pi = __shfl_xor(ai[e], m);
    ar[e] = take ? pr : ar[e];
    ai[e] = take ? pi : ai[e];
  });
}

__device__ __forceinline__ void cnot_wave(v16f& ar, v16f& ai, float2 (*ex)[NTH],
                                          const int tid, const int pt,
                                          const int ibase, const int c) {
  static_for<16>([&](auto ec) { constexpr int e = ec.value; ex[e][tid] = make_float2(ar[e], ai[e]); });
  __syncthreads();
  static_for<16>([&](auto ec) {
    constexpr int e = ec.value;
    const int take = ((ibase | e) >> c) & 1;
    const float2 p = ex[e][pt];
    ar[e] = take ? p.x : ar[e];
    ai[e] = take ? p.y : ai[e];
  });
  __syncthreads();
}

// ---------------- prep: 96 Rot matrices into gm ----------------
__global__ void qsim_prep(const float* __restrict__ w, float* __restrict__ gm) {
  const int i = threadIdx.x;
  if (i < 96) {
    const float phi = w[i * 3 + 0];
    const float th  = w[i * 3 + 1];
    const float om  = w[i * 3 + 2];
    float st, ct; sincosf(0.5f * th, &st, &ct);
    float sa, ca; sincosf(0.5f * (phi + om), &sa, &ca);
    float sb, cb; sincosf(0.5f * (phi - om), &sb, &cb);
    float* u = gm + i * 8;
    u[0] =  ct * ca; u[1] = -ct * sa;   // m00
    u[2] = -st * cb; u[3] = -st * sb;   // m01
    u[4] =  st * cb; u[5] = -st * sb;   // m10
    u[6] =  ct * ca; u[7] =  ct * sa;   // m11
  }
}

// ---------------- Sweep P: bits 0..12 in-tile, bits 13..15 fixed ----------------
// amp index i: bits 0..3 = local e, 4..9 = lane, 10..12 = wave, 13..15 = fb.
__global__ void __launch_bounds__(NTH) sweepP(float2* __restrict__ st,
                                              const float* __restrict__ x,
                                              const float* __restrict__ gm,
                                              const int l, const int do_init) {
  __shared__ float2 ex[16][NTH];  // 64 KB
  const int tid = threadIdx.x;
  const int s  = blockIdx.x >> 3;
  const int fb = blockIdx.x & 7;
  const int ibase = (fb << 13) | (tid << 4);
  float2* __restrict__ base = st + (s << 16) + ibase;

  v16f ar, ai;
  if (do_init) {
    // iv[q][0..3] = RX(x)|0> = (cos, 0, 0, -sin), aliased into ex
    float (*iv)[4] = reinterpret_cast<float(*)[4]>(&ex[0][0]);
    if (tid < 16) {
      float xs, xc; sincosf(0.5f * x[s * 16 + tid], &xs, &xc);
      iv[tid][0] = xc; iv[tid][1] = 0.f; iv[tid][2] = 0.f; iv[tid][3] = -xs;
    }
    __syncthreads();
    float Fr = 1.f, Fi = 0.f;
    #pragma unroll
    for (int b = 4; b < 16; ++b) {
      const int bit = (ibase >> b) & 1;
      const float fr = iv[b][2 * bit], fi = iv[b][2 * bit + 1];
      const float nr = Fr * fr - Fi * fi;
      Fi = Fr * fi + Fi * fr;
      Fr = nr;
    }
    ar[0] = Fr; ai[0] = Fi;
    static_for<4>([&](auto bc) {
      constexpr int bI = bc.value;
      const float xc = iv[bI][0];
      const float xs = -iv[bI][3];
      static_for<(1 << bI)>([&](auto kc) {
        constexpr int k = kc.value;
        constexpr int k1 = k | (1 << bI);
        const float kr = ar[k], ki = ai[k];
        ar[k1] = ki * xs; ai[k1] = -kr * xs;   // amp * (0, -xs)
        ar[k]  = kr * xc; ai[k]  = ki * xc;    // amp * (xc, 0)
      });
    });
    __syncthreads();  // iv dead; ex free for wave gates
  } else {
    const float4* __restrict__ p4 = reinterpret_cast<const float4*>(base);
    static_for<8>([&](auto kc) {
      constexpr int k = kc.value;
      const float4 v = p4[k];
      ar[2 * k] = v.x; ai[2 * k] = v.y; ar[2 * k + 1] = v.z; ai[2 * k + 1] = v.w;
    });
  }

  const int r = l + 1;
  const float* __restrict__ gl = gm + l * 128;
  // Rots q = 0..12
  static_for<4>([&](auto qc) { rot_local<qc.value>(ar, ai, gl + qc.value * 8); });
  #pragma unroll
  for (int q = 4; q < 10; ++q) rot_lane(ar, ai, gl + q * 8, 1 << (q - 4), (tid >> (q - 4)) & 1);
  #pragma unroll
  for (int q = 10; q < 13; ++q)
    rot_wave(ar, ai, gl + q * 8, ex, tid, tid ^ (1 << (q - 4)), (tid >> (q - 4)) & 1);
  // ring prefix g = 0 .. 12-r  (c = g, t = g+r <= 12)
  for (int g = 0; g <= 12 - r; ++g) {
    const int c = g, t = g + r;
    if (t < 4) {
      switch (t) {
        case 1: cnot_local<1>(ar, ai, ibase, c); break;
        case 2: cnot_local<2>(ar, ai, ibase, c); break;
        default: cnot_local<3>(ar, ai, ibase, c); break;
      }
    } else if (t < 10) {
      cnot_lane(ar, ai, 1 << (t - 4), ibase, c);
    } else {
      cnot_wave(ar, ai, ex, tid, tid ^ (1 << (t - 4)), ibase, c);
    }
  }

  float4* __restrict__ q4 = reinterpret_cast<float4*>(base);
  static_for<8>([&](auto kc) {
    constexpr int k = kc.value;
    q4[k] = make_float4(ar[2 * k], ai[2 * k], ar[2 * k + 1], ai[2 * k + 1]);
  });
}

// ---------------- Sweep Q: bits 0..6,10..15 in-tile, bits 7..9 fixed ----------------
// i: bits 0..3 = e, 4..6 = lane 0..2, 7..9 = fb, 10..12 = lane 3..5, 13..15 = wave.
__global__ void __launch_bounds__(NTH) sweepQ(float2* __restrict__ st,
                                              const float* __restrict__ gm,
                                              const int l) {
  __shared__ float2 ex[16][NTH];
  const int tid = threadIdx.x;
  const int s  = blockIdx.x >> 3;
  const int fb = blockIdx.x & 7;
  const int ibase = ((tid & 7) << 4) | (fb << 7) | (((tid >> 3) & 7) << 10) | ((tid >> 6) << 13);
  float2* __restrict__ base = st + (s << 16) + ibase;

  v16f ar, ai;
  const float4* __restrict__ p4 = reinterpret_cast<const float4*>(base);
  static_for<8>([&](auto kc) {
    constexpr int k = kc.value;
    const float4 v = p4[k];
    ar[2 * k] = v.x; ai[2 * k] = v.y; ar[2 * k + 1] = v.z; ai[2 * k + 1] = v.w;
  });

  const int r = l + 1;
  const float* __restrict__ gl = gm + l * 128;
  // Rots q = 13,14,15 (wave bits: tid bits 6..8)
  #pragma unroll
  for (int q = 13; q < 16; ++q)
    rot_wave(ar, ai, gl + q * 8, ex, tid, tid ^ (1 << (q - 7)), (tid >> (q - 7)) & 1);
  // ring suffix g = 13-r .. 15  (c = g in 7..15, t = (g+r)&15 in {13,14,15,0..r-1})
  for (int g = 13 - r; g < 16; ++g) {
    const int c = g, t = (g + r) & 15;
    if (t >= 13) {
      cnot_wave(ar, ai, ex, tid, tid ^ (1 << (t - 7)), ibase, c);
    } else if (t < 4) {
      switch (t) {
        case 0: cnot_local<0>(ar, ai, ibase, c); break;
        case 1: cnot_local<1>(ar, ai, ibase, c); break;
        case 2: cnot_local<2>(ar, ai, ibase, c); break;
        default: cnot_local<3>(ar, ai, ibase, c); break;
      }
    } else {  // t = 4 or 5 -> lane bits 0..1
      cnot_lane(ar, ai, 1 << (t - 4), ibase, c);
    }
  }

  float4* __restrict__ q4 = reinterpret_cast<float4*>(base);
  static_for<8>([&](auto kc) {
    constexpr int k = kc.value;
    q4[k] = make_float4(ar[2 * k], ai[2 * k], ar[2 * k + 1], ai[2 * k + 1]);
  });
}

// ---------------- measurement: <Z_q> per sample ----------------
__global__ void __launch_bounds__(NTH) measureK(const float2* __restrict__ st,
                                                float* __restrict__ out) {
  __shared__ float red[8][16];
  const int tid = threadIdx.x;
  const int s = blockIdx.x;
  const float4* __restrict__ p4 = reinterpret_cast<const float4*>(st + (s << 16) + tid * 128);

  float tot = 0.f;
  float sl0 = 0.f, sl1 = 0.f, sl2 = 0.f, sl3 = 0.f, sl4 = 0.f, sl5 = 0.f, sl6 = 0.f;
  static_for<64>([&](auto kc) {
    constexpr int k = kc.value;
    const float4 v = p4[k];
    static_for<2>([&](auto jc) {
      constexpr int c = 2 * k + jc.value;
      const float pr = (jc.value == 0) ? v.x : v.z;
      const float pi = (jc.value == 0) ? v.y : v.w;
      const float p = pr * pr + pi * pi;
      tot += p;
      if constexpr ((c & 1) != 0)  sl0 -= p; else sl0 += p;
      if constexpr ((c & 2) != 0)  sl1 -= p; else sl1 += p;
      if constexpr ((c & 4) != 0)  sl2 -= p; else sl2 += p;
      if constexpr ((c & 8) != 0)  sl3 -= p; else sl3 += p;
      if constexpr ((c & 16) != 0) sl4 -= p; else sl4 += p;
      if constexpr ((c & 32) != 0) sl5 -= p; else sl5 += p;
      if constexpr ((c & 64) != 0) sl6 -= p; else sl6 += p;
    });
  });

  const float sl[7] = {sl0, sl1, sl2, sl3, sl4, sl5, sl6};
  static_for<16>([&](auto qc) {
    constexpr int q = qc.value;  // qubit q <-> bit q; bits 7..15 come from tid
    float v;
    if constexpr (q < 7) v = sl[q];
    else v = ((tid >> (q - 7)) & 1) ? -tot : tot;
    v += __shfl_xor(v, 1);
    v += __shfl_xor(v, 2);
    v += __shfl_xor(v, 4);
    v += __shfl_xor(v, 8);
    v += __shfl_xor(v, 16);
    v += __shfl_xor(v, 32);
    if ((tid & 63) == 0) red[tid >> 6][q] = v;
  });
  __syncthreads();
  if (tid < 16) {
    float a = 0.f;
    #pragma unroll
    for (int wv = 0; wv < 8; ++wv) a += red[wv][tid];
    out[s * 16 + tid] = a;
  }
}

extern "C" void kernel_launch(void* const* d_in, const int* in_sizes, int n_in,
                              void* d_out, int out_size, void* d_ws, size_t ws_size,
                              hipStream_t stream) {
  (void)in_sizes; (void)n_in; (void)out_size;
  const float* x = (const float*)d_in[0];
  const float* w = (const float*)d_in[1];
  float* out = (float*)d_out;
  float* gm = (float*)d_ws;                      // 768 floats at offset 0
  float2* st = (float2*)((char*)d_ws + 65536);   // state, chunked to fit ws

  // samples per chunk bounded by available workspace (512 KB per sample)
  const size_t avail = ws_size > 65536 ? ws_size - 65536 : 0;
  long long chunk = (long long)(avail / 524288);
  if (chunk > 512) chunk = 512;
  if (chunk < 1) chunk = 1;  // no smaller option exists

  qsim_prep<<<dim3(1), dim3(128), 0, stream>>>(w, gm);
  for (int s0 = 0; s0 < 512; s0 += (int)chunk) {
    const int ns = (512 - s0) < (int)chunk ? (512 - s0) : (int)chunk;
    sweepP<<<dim3(ns * 8), dim3(NTH), 0, stream>>>(st, x + s0 * 16, gm, 0, 1);
    sweepQ<<<dim3(ns * 8), dim3(NTH), 0, stream>>>(st, gm, 0);
    for (int l = 1; l < 6; ++l) {
      sweepP<<<dim3(ns * 8), dim3(NTH), 0, stream>>>(st, x + s0 * 16, gm, l, 0);
      sweepQ<<<dim3(ns * 8), dim3(NTH), 0, stream>>>(st, gm, l);
    }
    measureK<<<dim3(ns), dim3(NTH), 0, stream>>>(st, out + s0 * 16);
  }
}